// Round 1
// baseline (53923.108 us; speedup 1.0000x reference)
//
#include <hip/hip_runtime.h>
#include <math.h>

#define B_  64
#define T_  512
#define D0_ 128
#define H_  512
#define G3_ 1536

// ---------------- scan kernel ----------------
// grid = 256 blocks (8 groups x 32 blocks), block = 384 threads (48 rows x 8 batch)
// Each group handles 8 batch elements; each block handles 16 hidden units
// (48 rows of W_hh, fp32, resident in LDS). Per-step cross-block exchange of
// h_new via global hist buffer + per-block flags (device-scope).
#define WSTR 516                      // padded row stride (floats) to kill bank conflicts
#define SCAN_LDS ((48*WSTR + 8*WSTR + 48*9 + 48)*4)

__global__ __launch_bounds__(384) void scan_kernel(
    const float* __restrict__ Whh, const float* __restrict__ bhh,
    const float* __restrict__ gx, float* __restrict__ hist,
    int* __restrict__ flags, int t0, int tc)
{
  extern __shared__ float sm[];
  float* Wsh  = sm;                 // [48][WSTR]
  float* hsh  = Wsh + 48*WSTR;      // [8][WSTR]
  float* ghsh = hsh + 8*WSTR;       // [48][9]
  float* bsh  = ghsh + 48*9;        // [48]

  const int tid = threadIdx.x;
  const int blk = blockIdx.x;
  const int g = blk >> 5, c = blk & 31;
  const int j0 = c << 4;            // 16 hidden units per block
  const int bbase = g << 3;         // 8 batches per group
  int* gflags = flags + g*32;

  // Load W_hh slice (rows {j0..j0+15} of each gate) into LDS, fp32.
  for (int idx = tid; idx < 48*128; idx += 384) {
    int r = idx >> 7; int kv = (idx & 127) << 2;
    int gate = r >> 4, jj = r & 15;
    *(float4*)(Wsh + r*WSTR + kv) =
      *(const float4*)(Whh + (size_t)(gate*H_ + j0 + jj)*H_ + kv);
  }
  if (tid < 48) {
    int gate = tid >> 4, jj = tid & 15;
    bsh[tid] = bhh[gate*H_ + j0 + jj];
  }
  __syncthreads();

  const int r = tid >> 3, b = tid & 7;   // one (row, batch) dot per thread
  const float* Wrow = Wsh + r*WSTR;
  const float* hrow = hsh + b*WSTR;

  for (int t = t0; t < t0 + tc; ++t) {
    // stage h_prev (full 512 per batch) into LDS
    if (t == 0) {
      for (int idx = tid; idx < 8*512; idx += 384)
        hsh[(idx>>9)*WSTR + (idx&511)] = 0.f;
    } else {
      for (int idx = tid; idx < 8*128; idx += 384) {
        int bb = idx >> 7, kv = (idx&127) << 2;
        *(float4*)(hsh + bb*WSTR + kv) =
          *(const float4*)(hist + ((size_t)(bbase+bb)*T_ + (t-1))*H_ + kv);
      }
    }
    __syncthreads();

    // gh[r][b] = dot(W_hh[row], h_prev[b]) + b_hh[row]
    float a0=0,a1=0,a2=0,a3=0,a4=0,a5=0,a6=0,a7=0;
    #pragma unroll 4
    for (int k = 0; k < 512; k += 8) {
      float4 w0 = *(const float4*)(Wrow + k);
      float4 h0 = *(const float4*)(hrow + k);
      float4 w1 = *(const float4*)(Wrow + k + 4);
      float4 h1 = *(const float4*)(hrow + k + 4);
      a0 += w0.x*h0.x; a1 += w0.y*h0.y; a2 += w0.z*h0.z; a3 += w0.w*h0.w;
      a4 += w1.x*h1.x; a5 += w1.y*h1.y; a6 += w1.z*h1.z; a7 += w1.w*h1.w;
    }
    ghsh[r*9 + b] = ((a0+a1)+(a2+a3)) + ((a4+a5)+(a6+a7)) + bsh[r];
    __syncthreads();

    // gates + h_new for this block's 16 units x 8 batches
    if (tid < 128) {
      int bb = tid >> 4, j = tid & 15;
      size_t go = ((size_t)(bbase+bb)*tc + (t - t0))*(size_t)G3_ + j0 + j;
      float gxr = gx[go], gxz = gx[go + 512], gxn = gx[go + 1024];
      float ghr = ghsh[ j      *9 + bb];
      float ghz = ghsh[(16 + j)*9 + bb];
      float ghn = ghsh[(32 + j)*9 + bb];
      float rg = 1.f/(1.f + expf(-(gxr + ghr)));
      float zg = 1.f/(1.f + expf(-(gxz + ghz)));
      float ng = tanhf(gxn + rg*ghn);
      float hp = hsh[bb*WSTR + j0 + j];
      hist[((size_t)(bbase+bb)*T_ + t)*H_ + j0 + j] = (1.f - zg)*ng + zg*hp;
    }
    // release our slice, then wait for the whole group
    __threadfence();
    __syncthreads();
    if (tid == 0)
      __hip_atomic_store(&gflags[c], t+1, __ATOMIC_RELEASE, __HIP_MEMORY_SCOPE_AGENT);
    if (tid < 32) {
      while (__hip_atomic_load(&gflags[tid], __ATOMIC_RELAXED,
                               __HIP_MEMORY_SCOPE_AGENT) < t+1) {}
    }
    __syncthreads();
    __threadfence();   // acquire: peers' hist writes visible before next staging
  }
}

// ---------------- gx GEMM ----------------
// gx[b,t,n] = sum_k A[b,t,k] * W_ih[n,k] + b_ih[n]
// 128x128 tile, kt=16, 256 threads, 8x8 micro-tile, fp32.
__global__ __launch_bounds__(256) void gemm_gx(
    const float* __restrict__ A, int lda,
    const float* __restrict__ W, const float* __restrict__ bias,
    float* __restrict__ gxout, int t0, int tc, int ltc)
{
  __shared__ float Ash[16][132];
  __shared__ float Bsh[16][132];
  const int tid = threadIdx.x;
  const int m0 = blockIdx.x << 7, n0 = blockIdx.y << 7;
  const int tx = tid & 15, ty = tid >> 4;

  const int ml = tid >> 1, kl = (tid & 1) << 3;
  const int m = m0 + ml;
  const float* arow = A + ((size_t)(m >> ltc)*T_ + t0 + (m & (tc-1)))*lda + kl;
  const float* brow = W + (size_t)(n0 + ml)*lda + kl;

  float acc[8][8] = {};
  for (int k0 = 0; k0 < lda; k0 += 16) {
    float4 av0 = *(const float4*)(arow + k0);
    float4 av1 = *(const float4*)(arow + k0 + 4);
    float4 bv0 = *(const float4*)(brow + k0);
    float4 bv1 = *(const float4*)(brow + k0 + 4);
    __syncthreads();
    Ash[kl+0][ml] = av0.x; Ash[kl+1][ml] = av0.y; Ash[kl+2][ml] = av0.z; Ash[kl+3][ml] = av0.w;
    Ash[kl+4][ml] = av1.x; Ash[kl+5][ml] = av1.y; Ash[kl+6][ml] = av1.z; Ash[kl+7][ml] = av1.w;
    Bsh[kl+0][ml] = bv0.x; Bsh[kl+1][ml] = bv0.y; Bsh[kl+2][ml] = bv0.z; Bsh[kl+3][ml] = bv0.w;
    Bsh[kl+4][ml] = bv1.x; Bsh[kl+5][ml] = bv1.y; Bsh[kl+6][ml] = bv1.z; Bsh[kl+7][ml] = bv1.w;
    __syncthreads();
    #pragma unroll
    for (int kk = 0; kk < 16; ++kk) {
      float4 a0 = *(const float4*)&Ash[kk][ty<<3];
      float4 a1 = *(const float4*)&Ash[kk][(ty<<3)+4];
      float4 b0 = *(const float4*)&Bsh[kk][tx<<3];
      float4 b1 = *(const float4*)&Bsh[kk][(tx<<3)+4];
      float av[8] = {a0.x,a0.y,a0.z,a0.w,a1.x,a1.y,a1.z,a1.w};
      float bv[8] = {b0.x,b0.y,b0.z,b0.w,b1.x,b1.y,b1.z,b1.w};
      #pragma unroll
      for (int i = 0; i < 8; ++i)
        #pragma unroll
        for (int j = 0; j < 8; ++j)
          acc[i][j] += av[i]*bv[j];
    }
  }

  float bv[8];
  #pragma unroll
  for (int j = 0; j < 8; ++j) bv[j] = bias[n0 + (tx<<3) + j];
  #pragma unroll
  for (int i = 0; i < 8; ++i) {
    int mm = m0 + (ty<<3) + i;
    float* orow = gxout + ((size_t)(mm >> ltc)*tc + (mm & (tc-1)))*(size_t)G3_
                  + n0 + (tx<<3);
    float4 o0 = make_float4(acc[i][0]+bv[0], acc[i][1]+bv[1],
                            acc[i][2]+bv[2], acc[i][3]+bv[3]);
    float4 o1 = make_float4(acc[i][4]+bv[4], acc[i][5]+bv[5],
                            acc[i][6]+bv[6], acc[i][7]+bv[7]);
    *(float4*)orow = o0;
    *(float4*)(orow+4) = o1;
  }
}

// ---------------- final FC ----------------
__global__ void fc_kernel(const float* __restrict__ hist, const float* __restrict__ Wfc,
                          const float* __restrict__ bfc, float* __restrict__ out)
{
  int b = blockIdx.x, lane = threadIdx.x;
  const float* h = hist + ((size_t)b*T_ + (T_-1))*H_;
  float acc = 0.f;
  for (int j = lane; j < H_; j += 64) acc += h[j]*Wfc[j];
  #pragma unroll
  for (int off = 32; off; off >>= 1) acc += __shfl_down(acc, off, 64);
  if (lane == 0) out[b] = acc + bfc[0];
}

__global__ void init_kernel(int* flags) {
  if (threadIdx.x < 512) flags[threadIdx.x] = 0;
}

extern "C" void kernel_launch(void* const* d_in, const int* in_sizes, int n_in,
                              void* d_out, int out_size, void* d_ws, size_t ws_size,
                              hipStream_t stream)
{
  const float* X    = (const float*)d_in[0];
  const float* Wih0 = (const float*)d_in[1];
  const float* Whh0 = (const float*)d_in[2];
  const float* bih0 = (const float*)d_in[3];
  const float* bhh0 = (const float*)d_in[4];
  const float* Wih1 = (const float*)d_in[5];
  const float* Whh1 = (const float*)d_in[6];
  const float* bih1 = (const float*)d_in[7];
  const float* bhh1 = (const float*)d_in[8];
  const float* Wfc  = (const float*)d_in[9];
  const float* bfc  = (const float*)d_in[10];

  // ws layout: [flags 4KB][hist 64*512*512*4 = 64MB][gx chunk buffer]
  int* flags = (int*)d_ws;
  float* hist = (float*)((char*)d_ws + 4096);
  const size_t histB = (size_t)B_*T_*H_*4;
  float* gxbuf = (float*)((char*)d_ws + 4096 + histB);

  int tc = 64;
  {
    size_t base = 4096 + histB;
    if      (ws_size >= base + (size_t)B_*512*G3_*4) tc = 512;
    else if (ws_size >= base + (size_t)B_*256*G3_*4) tc = 256;
    else if (ws_size >= base + (size_t)B_*128*G3_*4) tc = 128;
  }
  int ltc = 31 - __builtin_clz((unsigned)tc);

  hipFuncSetAttribute((const void*)scan_kernel,
      hipFuncAttributeMaxDynamicSharedMemorySize, SCAN_LDS);

  hipLaunchKernelGGL(init_kernel, dim3(1), dim3(512), 0, stream, flags);

  for (int lay = 0; lay < 2; ++lay) {
    const float* A   = lay ? (const float*)hist : X;
    int lda          = lay ? H_ : D0_;
    const float* Wih = lay ? Wih1 : Wih0;
    const float* bih = lay ? bih1 : bih0;
    const float* Whh = lay ? Whh1 : Whh0;
    const float* bhh = lay ? bhh1 : bhh0;
    int* lflags = flags + lay*256;
    for (int t0 = 0; t0 < T_; t0 += tc) {
      dim3 ggrid((B_*tc) >> 7, G3_ >> 7);
      hipLaunchKernelGGL(gemm_gx, ggrid, dim3(256), 0, stream,
                         A, lda, Wih, bih, gxbuf, t0, tc, ltc);
      const float* gxc = gxbuf;
      int t0a = t0, tca = tc;
      void* args[] = { (void*)&Whh, (void*)&bhh, (void*)&gxc, (void*)&hist,
                       (void*)&lflags, (void*)&t0a, (void*)&tca };
      hipLaunchCooperativeKernel((void*)scan_kernel, dim3(256), dim3(384),
                                 args, SCAN_LDS, stream);
    }
  }

  hipLaunchKernelGGL(fc_kernel, dim3(64), dim3(64), 0, stream,
                     (const float*)hist, Wfc, bfc, (float*)d_out);
}

// Round 2
// 5919.475 us; speedup vs baseline: 9.1094x; 9.1094x over previous
//
#include <hip/hip_runtime.h>
#include <math.h>

#define B_  64
#define T_  512
#define D0_ 128
#define H_  512
#define G3_ 1536
#define HSTR 512

// ---------------- scan kernel ----------------
// 256 blocks = 16 groups x 16 blocks. Group owns 4 batches; block owns 32
// hidden units (96 gate-rows of W_hh held in REGISTERS: 2 rows x 64 k per
// thread). Cross-block h exchange through L3 via relaxed agent-scope atomics
// (sc0|sc1 cache bypass) -- NO threadfence / L2 invalidate anywhere.
__global__ __launch_bounds__(384, 2) void scan_kernel(
    const float* __restrict__ Whh, const float* __restrict__ bhh,
    const float* __restrict__ gx, float* __restrict__ hist,
    int* __restrict__ flags, int t0, int tc)
{
  __shared__ float hsh[4 * HSTR];     // h_prev for 4 batches
  __shared__ float ghsh[96 * 5];      // gh partial-free results [row][batch(+pad)]
  __shared__ float bsh[96];           // b_hh slice

  const int tid = threadIdx.x;
  const int blk = blockIdx.x;
  const int g = blk >> 4, c = blk & 15;
  const int j0 = c << 5;              // 32 hidden units per block
  const int bbase = g << 2;           // 4 batches per group
  int* gflags = flags + g * 16;

  // thread decomposition: rp in [0,48) row-pair, s in [0,8) k-slice
  const int rp = tid >> 3, s = tid & 7;
  const int r0 = rp, r1 = rp + 48;                 // gate-rows in [0,96)
  const int grow0 = (r0 >> 5) * H_ + j0 + (r0 & 31);
  const int grow1 = (r1 >> 5) * H_ + j0 + (r1 & 31);

  // W_hh rows -> registers. Thread s covers k-granules {kk*8+s}, i.e. float
  // k = kk*32 + s*4 + c. Makes the per-step LDS h reads 16-consecutive-granule
  // (bank-conflict-free).
  float w0[64], w1[64];
  {
    const float* R0 = Whh + (size_t)grow0 * H_ + (s << 2);
    const float* R1 = Whh + (size_t)grow1 * H_ + (s << 2);
    #pragma unroll
    for (int kk = 0; kk < 16; ++kk) {
      *(float4*)&w0[kk * 4] = *(const float4*)(R0 + kk * 32);
      *(float4*)&w1[kk * 4] = *(const float4*)(R1 + kk * 32);
    }
  }
  if (tid < 96)
    bsh[tid] = bhh[(tid >> 5) * H_ + j0 + (tid & 31)];
  __syncthreads();

  for (int t = t0; t < t0 + tc; ++t) {
    // ---- stage h_prev into LDS ----
    if (t == 0) {
      for (int idx = tid; idx < 4 * H_; idx += 384)
        hsh[(idx >> 9) * HSTR + (idx & 511)] = 0.f;
    } else {
      // 64-bit agent-scope atomic loads: bypass L1/L2, read L3-current data.
      for (int idx = tid; idx < 1024; idx += 384) {
        int bb = idx >> 8, e2 = idx & 255;
        const unsigned long long* src = (const unsigned long long*)
            (hist + ((size_t)(bbase + bb) * T_ + (t - 1)) * H_) + e2;
        unsigned long long v = __hip_atomic_load(src, __ATOMIC_RELAXED,
                                                 __HIP_MEMORY_SCOPE_AGENT);
        *(unsigned long long*)&hsh[bb * HSTR + (e2 << 1)] = v;
      }
    }
    __syncthreads();

    // ---- partial dots: 2 rows x 4 batches, k-slice of 64 per thread ----
    float acc0[4], acc1[4];
    #pragma unroll
    for (int b = 0; b < 4; ++b) {
      const float* hb = hsh + b * HSTR + (s << 2);
      float a00 = 0.f, a01 = 0.f, a10 = 0.f, a11 = 0.f;
      #pragma unroll
      for (int kk = 0; kk < 16; kk += 2) {
        float4 h0 = *(const float4*)(hb + kk * 32);
        float4 h1 = *(const float4*)(hb + kk * 32 + 32);
        a00 += w0[kk*4+0]*h0.x; a00 += w0[kk*4+1]*h0.y;
        a00 += w0[kk*4+2]*h0.z; a00 += w0[kk*4+3]*h0.w;
        a10 += w1[kk*4+0]*h0.x; a10 += w1[kk*4+1]*h0.y;
        a10 += w1[kk*4+2]*h0.z; a10 += w1[kk*4+3]*h0.w;
        a01 += w0[kk*4+4]*h1.x; a01 += w0[kk*4+5]*h1.y;
        a01 += w0[kk*4+6]*h1.z; a01 += w0[kk*4+7]*h1.w;
        a11 += w1[kk*4+4]*h1.x; a11 += w1[kk*4+5]*h1.y;
        a11 += w1[kk*4+6]*h1.z; a11 += w1[kk*4+7]*h1.w;
      }
      acc0[b] = a00 + a01;
      acc1[b] = a10 + a11;
    }

    // ---- reduce over the 8 k-slice lanes (xor shuffle) ----
    #pragma unroll
    for (int m = 1; m < 8; m <<= 1) {
      #pragma unroll
      for (int b = 0; b < 4; ++b) {
        acc0[b] += __shfl_xor(acc0[b], m, 64);
        acc1[b] += __shfl_xor(acc1[b], m, 64);
      }
    }
    if (s < 4) {   // lane s writes batch s (cndmask selects, no dyn index)
      float v0 = (s & 2) ? ((s & 1) ? acc0[3] : acc0[2])
                         : ((s & 1) ? acc0[1] : acc0[0]);
      float v1 = (s & 2) ? ((s & 1) ? acc1[3] : acc1[2])
                         : ((s & 1) ? acc1[1] : acc1[0]);
      ghsh[r0 * 5 + s] = v0;
      ghsh[r1 * 5 + s] = v1;
    }
    __syncthreads();

    // ---- gates + h_new: 32 units x 4 batches ----
    if (tid < 128) {
      int bb = tid >> 5, j = tid & 31;
      size_t go = ((size_t)(bbase + bb) * tc + (t - t0)) * (size_t)G3_ + j0 + j;
      float gxr = gx[go], gxz = gx[go + 512], gxn = gx[go + 1024];
      float ghr = ghsh[ j       * 5 + bb] + bsh[j];
      float ghz = ghsh[(32 + j) * 5 + bb] + bsh[32 + j];
      float ghn = ghsh[(64 + j) * 5 + bb] + bsh[64 + j];
      float rg = 1.f / (1.f + expf(-(gxr + ghr)));
      float zg = 1.f / (1.f + expf(-(gxz + ghz)));
      float ng = tanhf(gxn + rg * ghn);
      float hp = hsh[bb * HSTR + j0 + j];
      float hnew = (1.f - zg) * ng + zg * hp;
      __hip_atomic_store(&hist[((size_t)(bbase + bb) * T_ + t) * H_ + j0 + j],
                         hnew, __ATOMIC_RELAXED, __HIP_MEMORY_SCOPE_AGENT);
    }

    // ---- group barrier: drain stores, publish flag, spin on 16 flags ----
    asm volatile("s_waitcnt vmcnt(0)" ::: "memory");
    __syncthreads();          // all waves' stores are at the coherence point
    if (tid == 0)
      __hip_atomic_store(&gflags[c], t + 1, __ATOMIC_RELAXED,
                         __HIP_MEMORY_SCOPE_AGENT);
    if (tid < 16) {
      while (__hip_atomic_load(&gflags[tid], __ATOMIC_RELAXED,
                               __HIP_MEMORY_SCOPE_AGENT) < t + 1) {}
    }
    __syncthreads();
    asm volatile("" ::: "memory");   // no load hoisting above the spin
  }
}

// ---------------- gx GEMM ----------------
__global__ __launch_bounds__(256) void gemm_gx(
    const float* __restrict__ A, int lda,
    const float* __restrict__ W, const float* __restrict__ bias,
    float* __restrict__ gxout, int t0, int tc, int ltc)
{
  __shared__ float Ash[16][132];
  __shared__ float Bsh[16][132];
  const int tid = threadIdx.x;
  const int m0 = blockIdx.x << 7, n0 = blockIdx.y << 7;
  const int tx = tid & 15, ty = tid >> 4;

  const int ml = tid >> 1, kl = (tid & 1) << 3;
  const int m = m0 + ml;
  const float* arow = A + ((size_t)(m >> ltc)*T_ + t0 + (m & (tc-1)))*lda + kl;
  const float* brow = W + (size_t)(n0 + ml)*lda + kl;

  float acc[8][8] = {};
  for (int k0 = 0; k0 < lda; k0 += 16) {
    float4 av0 = *(const float4*)(arow + k0);
    float4 av1 = *(const float4*)(arow + k0 + 4);
    float4 bv0 = *(const float4*)(brow + k0);
    float4 bv1 = *(const float4*)(brow + k0 + 4);
    __syncthreads();
    Ash[kl+0][ml] = av0.x; Ash[kl+1][ml] = av0.y; Ash[kl+2][ml] = av0.z; Ash[kl+3][ml] = av0.w;
    Ash[kl+4][ml] = av1.x; Ash[kl+5][ml] = av1.y; Ash[kl+6][ml] = av1.z; Ash[kl+7][ml] = av1.w;
    Bsh[kl+0][ml] = bv0.x; Bsh[kl+1][ml] = bv0.y; Bsh[kl+2][ml] = bv0.z; Bsh[kl+3][ml] = bv0.w;
    Bsh[kl+4][ml] = bv1.x; Bsh[kl+5][ml] = bv1.y; Bsh[kl+6][ml] = bv1.z; Bsh[kl+7][ml] = bv1.w;
    __syncthreads();
    #pragma unroll
    for (int kk = 0; kk < 16; ++kk) {
      float4 a0 = *(const float4*)&Ash[kk][ty<<3];
      float4 a1 = *(const float4*)&Ash[kk][(ty<<3)+4];
      float4 b0 = *(const float4*)&Bsh[kk][tx<<3];
      float4 b1 = *(const float4*)&Bsh[kk][(tx<<3)+4];
      float av[8] = {a0.x,a0.y,a0.z,a0.w,a1.x,a1.y,a1.z,a1.w};
      float bv[8] = {b0.x,b0.y,b0.z,b0.w,b1.x,b1.y,b1.z,b1.w};
      #pragma unroll
      for (int i = 0; i < 8; ++i)
        #pragma unroll
        for (int j = 0; j < 8; ++j)
          acc[i][j] += av[i]*bv[j];
    }
  }

  float bv[8];
  #pragma unroll
  for (int j = 0; j < 8; ++j) bv[j] = bias[n0 + (tx<<3) + j];
  #pragma unroll
  for (int i = 0; i < 8; ++i) {
    int mm = m0 + (ty<<3) + i;
    float* orow = gxout + ((size_t)(mm >> ltc)*tc + (mm & (tc-1)))*(size_t)G3_
                  + n0 + (tx<<3);
    float4 o0 = make_float4(acc[i][0]+bv[0], acc[i][1]+bv[1],
                            acc[i][2]+bv[2], acc[i][3]+bv[3]);
    float4 o1 = make_float4(acc[i][4]+bv[4], acc[i][5]+bv[5],
                            acc[i][6]+bv[6], acc[i][7]+bv[7]);
    *(float4*)orow = o0;
    *(float4*)(orow+4) = o1;
  }
}

// ---------------- final FC ----------------
__global__ void fc_kernel(const float* __restrict__ hist, const float* __restrict__ Wfc,
                          const float* __restrict__ bfc, float* __restrict__ out)
{
  int b = blockIdx.x, lane = threadIdx.x;
  const float* h = hist + ((size_t)b*T_ + (T_-1))*H_;
  float acc = 0.f;
  for (int j = lane; j < H_; j += 64) acc += h[j]*Wfc[j];
  #pragma unroll
  for (int off = 32; off; off >>= 1) acc += __shfl_down(acc, off, 64);
  if (lane == 0) out[b] = acc + bfc[0];
}

__global__ void init_kernel(int* flags) {
  if (threadIdx.x < 512) flags[threadIdx.x] = 0;
}

extern "C" void kernel_launch(void* const* d_in, const int* in_sizes, int n_in,
                              void* d_out, int out_size, void* d_ws, size_t ws_size,
                              hipStream_t stream)
{
  const float* X    = (const float*)d_in[0];
  const float* Wih0 = (const float*)d_in[1];
  const float* Whh0 = (const float*)d_in[2];
  const float* bih0 = (const float*)d_in[3];
  const float* bhh0 = (const float*)d_in[4];
  const float* Wih1 = (const float*)d_in[5];
  const float* Whh1 = (const float*)d_in[6];
  const float* bih1 = (const float*)d_in[7];
  const float* bhh1 = (const float*)d_in[8];
  const float* Wfc  = (const float*)d_in[9];
  const float* bfc  = (const float*)d_in[10];

  int* flags = (int*)d_ws;
  float* hist = (float*)((char*)d_ws + 4096);
  const size_t histB = (size_t)B_*T_*H_*4;
  float* gxbuf = (float*)((char*)d_ws + 4096 + histB);

  int tc = 64;
  {
    size_t base = 4096 + histB;
    if      (ws_size >= base + (size_t)B_*512*G3_*4) tc = 512;
    else if (ws_size >= base + (size_t)B_*256*G3_*4) tc = 256;
    else if (ws_size >= base + (size_t)B_*128*G3_*4) tc = 128;
  }
  int ltc = 31 - __builtin_clz((unsigned)tc);

  hipLaunchKernelGGL(init_kernel, dim3(1), dim3(512), 0, stream, flags);

  for (int lay = 0; lay < 2; ++lay) {
    const float* A   = lay ? (const float*)hist : X;
    int lda          = lay ? H_ : D0_;
    const float* Wih = lay ? Wih1 : Wih0;
    const float* bih = lay ? bih1 : bih0;
    const float* Whh = lay ? Whh1 : Whh0;
    const float* bhh = lay ? bhh1 : bhh0;
    int* lflags = flags + lay*256;
    for (int t0 = 0; t0 < T_; t0 += tc) {
      dim3 ggrid((B_*tc) >> 7, G3_ >> 7);
      hipLaunchKernelGGL(gemm_gx, ggrid, dim3(256), 0, stream,
                         A, lda, Wih, bih, gxbuf, t0, tc, ltc);
      const float* gxc = gxbuf;
      int t0a = t0, tca = tc;
      void* args[] = { (void*)&Whh, (void*)&bhh, (void*)&gxc, (void*)&hist,
                       (void*)&lflags, (void*)&t0a, (void*)&tca };
      hipLaunchCooperativeKernel((void*)scan_kernel, dim3(256), dim3(384),
                                 args, 0, stream);
    }
  }

  hipLaunchKernelGGL(fc_kernel, dim3(64), dim3(64), 0, stream,
                     (const float*)hist, Wfc, bfc, (float*)d_out);
}

// Round 3
// 5674.324 us; speedup vs baseline: 9.5030x; 1.0432x over previous
//
#include <hip/hip_runtime.h>
#include <math.h>

#define B_  64
#define T_  512
#define D0_ 128
#define H_  512
#define G3_ 1536
#define HSTR 512

// ---------------- scan kernel ----------------
// 256 blocks = 16 groups x 16 blocks. Group owns 4 batches; block owns 32
// hidden units (96 gate-rows of W_hh in REGISTERS: 2 rows x 64 k per thread).
// Cross-block h exchange through L3 via relaxed agent-scope atomics -- no
// threadfence / L2 invalidate anywhere. gx[t] prefetched at step start.
__global__ __launch_bounds__(384, 2) void scan_kernel(
    const float* __restrict__ Whh, const float* __restrict__ bhh,
    const float* __restrict__ gx, float* __restrict__ hist,
    int* __restrict__ flags, int t0, int tc)
{
  __shared__ float hsh[4 * HSTR];     // h_prev for 4 batches
  __shared__ float ghsh[96 * 5];      // gh results [row][batch(+pad)]
  __shared__ float bsh[96];           // b_hh slice

  const int tid = threadIdx.x;
  const int blk = blockIdx.x;
  const int g = blk >> 4, c = blk & 15;
  const int j0 = c << 5;              // 32 hidden units per block
  const int bbase = g << 2;           // 4 batches per group
  int* gflags = flags + g * 16;

  const int rp = tid >> 3, s = tid & 7;
  const int r0 = rp, r1 = rp + 48;
  const int grow0 = (r0 >> 5) * H_ + j0 + (r0 & 31);
  const int grow1 = (r1 >> 5) * H_ + j0 + (r1 & 31);

  float w0[64], w1[64];
  {
    const float* R0 = Whh + (size_t)grow0 * H_ + (s << 2);
    const float* R1 = Whh + (size_t)grow1 * H_ + (s << 2);
    #pragma unroll
    for (int kk = 0; kk < 16; ++kk) {
      *(float4*)&w0[kk * 4] = *(const float4*)(R0 + kk * 32);
      *(float4*)&w1[kk * 4] = *(const float4*)(R1 + kk * 32);
    }
  }
  if (tid < 96)
    bsh[tid] = bhh[(tid >> 5) * H_ + j0 + (tid & 31)];

  // gx base offset for the gate phase (threads 0..127)
  size_t go0 = 0;
  if (tid < 128) {
    int bb = tid >> 5, j = tid & 31;
    go0 = ((size_t)(bbase + bb) * tc) * (size_t)G3_ + j0 + j;
  }
  __syncthreads();

  for (int t = t0; t < t0 + tc; ++t) {
    // ---- prefetch gx[t] (no dependence on peers -- overlaps staging+dots)
    float gxr = 0.f, gxz = 0.f, gxn = 0.f;
    if (tid < 128) {
      size_t go = go0 + (size_t)(t - t0) * (size_t)G3_;
      gxr = gx[go]; gxz = gx[go + 512]; gxn = gx[go + 1024];
    }

    // ---- stage h_prev into LDS ----
    if (t == 0) {
      for (int idx = tid; idx < 4 * H_; idx += 384)
        hsh[(idx >> 9) * HSTR + (idx & 511)] = 0.f;
    } else {
      for (int idx = tid; idx < 1024; idx += 384) {
        int bb = idx >> 8, e2 = idx & 255;
        const unsigned long long* src = (const unsigned long long*)
            (hist + ((size_t)(bbase + bb) * T_ + (t - 1)) * H_) + e2;
        unsigned long long v = __hip_atomic_load(src, __ATOMIC_RELAXED,
                                                 __HIP_MEMORY_SCOPE_AGENT);
        *(unsigned long long*)&hsh[bb * HSTR + (e2 << 1)] = v;
      }
    }
    __syncthreads();

    // ---- partial dots: 2 rows x 4 batches, k-slice of 64 per thread ----
    float acc0[4], acc1[4];
    #pragma unroll
    for (int b = 0; b < 4; ++b) {
      const float* hb = hsh + b * HSTR + (s << 2);
      float a00 = 0.f, a01 = 0.f, a10 = 0.f, a11 = 0.f;
      #pragma unroll
      for (int kk = 0; kk < 16; kk += 2) {
        float4 h0 = *(const float4*)(hb + kk * 32);
        float4 h1 = *(const float4*)(hb + kk * 32 + 32);
        a00 += w0[kk*4+0]*h0.x; a00 += w0[kk*4+1]*h0.y;
        a00 += w0[kk*4+2]*h0.z; a00 += w0[kk*4+3]*h0.w;
        a10 += w1[kk*4+0]*h0.x; a10 += w1[kk*4+1]*h0.y;
        a10 += w1[kk*4+2]*h0.z; a10 += w1[kk*4+3]*h0.w;
        a01 += w0[kk*4+4]*h1.x; a01 += w0[kk*4+5]*h1.y;
        a01 += w0[kk*4+6]*h1.z; a01 += w0[kk*4+7]*h1.w;
        a11 += w1[kk*4+4]*h1.x; a11 += w1[kk*4+5]*h1.y;
        a11 += w1[kk*4+6]*h1.z; a11 += w1[kk*4+7]*h1.w;
      }
      acc0[b] = a00 + a01;
      acc1[b] = a10 + a11;
    }

    #pragma unroll
    for (int m = 1; m < 8; m <<= 1) {
      #pragma unroll
      for (int b = 0; b < 4; ++b) {
        acc0[b] += __shfl_xor(acc0[b], m, 64);
        acc1[b] += __shfl_xor(acc1[b], m, 64);
      }
    }
    if (s < 4) {
      float v0 = (s & 2) ? ((s & 1) ? acc0[3] : acc0[2])
                         : ((s & 1) ? acc0[1] : acc0[0]);
      float v1 = (s & 2) ? ((s & 1) ? acc1[3] : acc1[2])
                         : ((s & 1) ? acc1[1] : acc1[0]);
      ghsh[r0 * 5 + s] = v0;
      ghsh[r1 * 5 + s] = v1;
    }
    __syncthreads();

    // ---- gates + h_new: 32 units x 4 batches ----
    if (tid < 128) {
      int bb = tid >> 5, j = tid & 31;
      float ghr = ghsh[ j       * 5 + bb] + bsh[j];
      float ghz = ghsh[(32 + j) * 5 + bb] + bsh[32 + j];
      float ghn = ghsh[(64 + j) * 5 + bb] + bsh[64 + j];
      float rg = 1.f / (1.f + expf(-(gxr + ghr)));
      float zg = 1.f / (1.f + expf(-(gxz + ghz)));
      float ng = tanhf(gxn + rg * ghn);
      float hp = hsh[bb * HSTR + j0 + j];
      float hnew = (1.f - zg) * ng + zg * hp;
      __hip_atomic_store(&hist[((size_t)(bbase + bb) * T_ + t) * H_ + j0 + j],
                         hnew, __ATOMIC_RELAXED, __HIP_MEMORY_SCOPE_AGENT);
    }

    // ---- group barrier ----
    asm volatile("s_waitcnt vmcnt(0)" ::: "memory");
    __syncthreads();
    if (tid == 0)
      __hip_atomic_store(&gflags[c], t + 1, __ATOMIC_RELAXED,
                         __HIP_MEMORY_SCOPE_AGENT);
    if (tid < 16) {
      while (__hip_atomic_load(&gflags[tid], __ATOMIC_RELAXED,
                               __HIP_MEMORY_SCOPE_AGENT) < t + 1) {}
    }
    __syncthreads();
    asm volatile("" ::: "memory");
  }
}

// ---------------- gx GEMM (software-pipelined) ----------------
// Pipeline: regs->LDS, sync, issue NEXT global loads, compute -- next-tile
// latency hides behind the 2048-cycle FMA block.
__global__ __launch_bounds__(256, 2) void gemm_gx(
    const float* __restrict__ A, int lda,
    const float* __restrict__ W, const float* __restrict__ bias,
    float* __restrict__ gxout, int t0, int tc, int ltc)
{
  __shared__ float Ash[16][132];
  __shared__ float Bsh[16][132];
  const int tid = threadIdx.x;
  const int m0 = blockIdx.x << 7, n0 = blockIdx.y << 7;
  const int tx = tid & 15, ty = tid >> 4;

  const int ml = tid >> 1, kl = (tid & 1) << 3;
  const int m = m0 + ml;
  const float* arow = A + ((size_t)(m >> ltc)*T_ + t0 + (m & (tc-1)))*lda + kl;
  const float* brow = W + (size_t)(n0 + ml)*lda + kl;

  float4 av0 = *(const float4*)(arow);
  float4 av1 = *(const float4*)(arow + 4);
  float4 bv0 = *(const float4*)(brow);
  float4 bv1 = *(const float4*)(brow + 4);

  float acc[8][8] = {};
  for (int k0 = 0; k0 < lda; k0 += 16) {
    __syncthreads();
    Ash[kl+0][ml] = av0.x; Ash[kl+1][ml] = av0.y; Ash[kl+2][ml] = av0.z; Ash[kl+3][ml] = av0.w;
    Ash[kl+4][ml] = av1.x; Ash[kl+5][ml] = av1.y; Ash[kl+6][ml] = av1.z; Ash[kl+7][ml] = av1.w;
    Bsh[kl+0][ml] = bv0.x; Bsh[kl+1][ml] = bv0.y; Bsh[kl+2][ml] = bv0.z; Bsh[kl+3][ml] = bv0.w;
    Bsh[kl+4][ml] = bv1.x; Bsh[kl+5][ml] = bv1.y; Bsh[kl+6][ml] = bv1.z; Bsh[kl+7][ml] = bv1.w;
    __syncthreads();

    int kn = (k0 + 16 < lda) ? k0 + 16 : k0;   // uniform; last iter reloads (harmless)
    av0 = *(const float4*)(arow + kn);
    av1 = *(const float4*)(arow + kn + 4);
    bv0 = *(const float4*)(brow + kn);
    bv1 = *(const float4*)(brow + kn + 4);

    #pragma unroll
    for (int kk = 0; kk < 16; ++kk) {
      float4 a0 = *(const float4*)&Ash[kk][ty<<3];
      float4 a1 = *(const float4*)&Ash[kk][(ty<<3)+4];
      float4 b0 = *(const float4*)&Bsh[kk][tx<<3];
      float4 b1 = *(const float4*)&Bsh[kk][(tx<<3)+4];
      float av[8] = {a0.x,a0.y,a0.z,a0.w,a1.x,a1.y,a1.z,a1.w};
      float bv[8] = {b0.x,b0.y,b0.z,b0.w,b1.x,b1.y,b1.z,b1.w};
      #pragma unroll
      for (int i = 0; i < 8; ++i)
        #pragma unroll
        for (int j = 0; j < 8; ++j)
          acc[i][j] += av[i]*bv[j];
    }
  }

  float bv[8];
  #pragma unroll
  for (int j = 0; j < 8; ++j) bv[j] = bias[n0 + (tx<<3) + j];
  #pragma unroll
  for (int i = 0; i < 8; ++i) {
    int mm = m0 + (ty<<3) + i;
    float* orow = gxout + ((size_t)(mm >> ltc)*tc + (mm & (tc-1)))*(size_t)G3_
                  + n0 + (tx<<3);
    float4 o0 = make_float4(acc[i][0]+bv[0], acc[i][1]+bv[1],
                            acc[i][2]+bv[2], acc[i][3]+bv[3]);
    float4 o1 = make_float4(acc[i][4]+bv[4], acc[i][5]+bv[5],
                            acc[i][6]+bv[6], acc[i][7]+bv[7]);
    *(float4*)orow = o0;
    *(float4*)(orow+4) = o1;
  }
}

// ---------------- final FC ----------------
__global__ void fc_kernel(const float* __restrict__ hist, const float* __restrict__ Wfc,
                          const float* __restrict__ bfc, float* __restrict__ out)
{
  int b = blockIdx.x, lane = threadIdx.x;
  const float* h = hist + ((size_t)b*T_ + (T_-1))*H_;
  float acc = 0.f;
  for (int j = lane; j < H_; j += 64) acc += h[j]*Wfc[j];
  #pragma unroll
  for (int off = 32; off; off >>= 1) acc += __shfl_down(acc, off, 64);
  if (lane == 0) out[b] = acc + bfc[0];
}

__global__ void init_kernel(int* flags) {
  if (threadIdx.x < 512) flags[threadIdx.x] = 0;
}

extern "C" void kernel_launch(void* const* d_in, const int* in_sizes, int n_in,
                              void* d_out, int out_size, void* d_ws, size_t ws_size,
                              hipStream_t stream)
{
  const float* X    = (const float*)d_in[0];
  const float* Wih0 = (const float*)d_in[1];
  const float* Whh0 = (const float*)d_in[2];
  const float* bih0 = (const float*)d_in[3];
  const float* bhh0 = (const float*)d_in[4];
  const float* Wih1 = (const float*)d_in[5];
  const float* Whh1 = (const float*)d_in[6];
  const float* bih1 = (const float*)d_in[7];
  const float* bhh1 = (const float*)d_in[8];
  const float* Wfc  = (const float*)d_in[9];
  const float* bfc  = (const float*)d_in[10];

  int* flags = (int*)d_ws;
  float* hist = (float*)((char*)d_ws + 4096);
  const size_t histB = (size_t)B_*T_*H_*4;
  float* gxbuf = (float*)((char*)d_ws + 4096 + histB);

  int tc = 64;
  {
    size_t base = 4096 + histB;
    if      (ws_size >= base + (size_t)B_*512*G3_*4) tc = 512;
    else if (ws_size >= base + (size_t)B_*256*G3_*4) tc = 256;
    else if (ws_size >= base + (size_t)B_*128*G3_*4) tc = 128;
  }
  int ltc = 31 - __builtin_clz((unsigned)tc);

  hipLaunchKernelGGL(init_kernel, dim3(1), dim3(512), 0, stream, flags);

  for (int lay = 0; lay < 2; ++lay) {
    const float* A   = lay ? (const float*)hist : X;
    int lda          = lay ? H_ : D0_;
    const float* Wih = lay ? Wih1 : Wih0;
    const float* bih = lay ? bih1 : bih0;
    const float* Whh = lay ? Whh1 : Whh0;
    const float* bhh = lay ? bhh1 : bhh0;
    int* lflags = flags + lay*256;
    for (int t0 = 0; t0 < T_; t0 += tc) {
      dim3 ggrid((B_*tc) >> 7, G3_ >> 7);
      hipLaunchKernelGGL(gemm_gx, ggrid, dim3(256), 0, stream,
                         A, lda, Wih, bih, gxbuf, t0, tc, ltc);
      const float* gxc = gxbuf;
      int t0a = t0, tca = tc;
      void* args[] = { (void*)&Whh, (void*)&bhh, (void*)&gxc, (void*)&hist,
                       (void*)&lflags, (void*)&t0a, (void*)&tca };
      hipLaunchCooperativeKernel((void*)scan_kernel, dim3(256), dim3(384),
                                 args, 0, stream);
    }
  }

  hipLaunchKernelGGL(fc_kernel, dim3(64), dim3(64), 0, stream,
                     (const float*)hist, Wfc, bfc, (float*)d_out);
}

// Round 4
// 5380.362 us; speedup vs baseline: 10.0222x; 1.0546x over previous
//
#include <hip/hip_runtime.h>
#include <math.h>

#define B_  64
#define T_  512
#define D0_ 128
#define H_  512
#define G3_ 1536
#define HSTR 512
#define BK  32

typedef short short8 __attribute__((ext_vector_type(8)));
typedef float f32x4 __attribute__((ext_vector_type(4)));

// ---------------- scan kernel (unchanged from R2 -- proven 1255 us) --------
__global__ __launch_bounds__(384, 2) void scan_kernel(
    const float* __restrict__ Whh, const float* __restrict__ bhh,
    const float* __restrict__ gx, float* __restrict__ hist,
    int* __restrict__ flags, int t0, int tc)
{
  __shared__ float hsh[4 * HSTR];
  __shared__ float ghsh[96 * 5];
  __shared__ float bsh[96];

  const int tid = threadIdx.x;
  const int blk = blockIdx.x;
  const int g = blk >> 4, c = blk & 15;
  const int j0 = c << 5;
  const int bbase = g << 2;
  int* gflags = flags + g * 16;

  const int rp = tid >> 3, s = tid & 7;
  const int r0 = rp, r1 = rp + 48;
  const int grow0 = (r0 >> 5) * H_ + j0 + (r0 & 31);
  const int grow1 = (r1 >> 5) * H_ + j0 + (r1 & 31);

  float w0[64], w1[64];
  {
    const float* R0 = Whh + (size_t)grow0 * H_ + (s << 2);
    const float* R1 = Whh + (size_t)grow1 * H_ + (s << 2);
    #pragma unroll
    for (int kk = 0; kk < 16; ++kk) {
      *(float4*)&w0[kk * 4] = *(const float4*)(R0 + kk * 32);
      *(float4*)&w1[kk * 4] = *(const float4*)(R1 + kk * 32);
    }
  }
  if (tid < 96)
    bsh[tid] = bhh[(tid >> 5) * H_ + j0 + (tid & 31)];

  size_t go0 = 0;
  if (tid < 128) {
    int bb = tid >> 5, j = tid & 31;
    go0 = ((size_t)(bbase + bb) * tc) * (size_t)G3_ + j0 + j;
  }
  __syncthreads();

  for (int t = t0; t < t0 + tc; ++t) {
    float gxr = 0.f, gxz = 0.f, gxn = 0.f;
    if (tid < 128) {
      size_t go = go0 + (size_t)(t - t0) * (size_t)G3_;
      gxr = gx[go]; gxz = gx[go + 512]; gxn = gx[go + 1024];
    }

    if (t == 0) {
      for (int idx = tid; idx < 4 * H_; idx += 384)
        hsh[(idx >> 9) * HSTR + (idx & 511)] = 0.f;
    } else {
      for (int idx = tid; idx < 1024; idx += 384) {
        int bb = idx >> 8, e2 = idx & 255;
        const unsigned long long* src = (const unsigned long long*)
            (hist + ((size_t)(bbase + bb) * T_ + (t - 1)) * H_) + e2;
        unsigned long long v = __hip_atomic_load(src, __ATOMIC_RELAXED,
                                                 __HIP_MEMORY_SCOPE_AGENT);
        *(unsigned long long*)&hsh[bb * HSTR + (e2 << 1)] = v;
      }
    }
    __syncthreads();

    float acc0[4], acc1[4];
    #pragma unroll
    for (int b = 0; b < 4; ++b) {
      const float* hb = hsh + b * HSTR + (s << 2);
      float a00 = 0.f, a01 = 0.f, a10 = 0.f, a11 = 0.f;
      #pragma unroll
      for (int kk = 0; kk < 16; kk += 2) {
        float4 h0 = *(const float4*)(hb + kk * 32);
        float4 h1 = *(const float4*)(hb + kk * 32 + 32);
        a00 += w0[kk*4+0]*h0.x; a00 += w0[kk*4+1]*h0.y;
        a00 += w0[kk*4+2]*h0.z; a00 += w0[kk*4+3]*h0.w;
        a10 += w1[kk*4+0]*h0.x; a10 += w1[kk*4+1]*h0.y;
        a10 += w1[kk*4+2]*h0.z; a10 += w1[kk*4+3]*h0.w;
        a01 += w0[kk*4+4]*h1.x; a01 += w0[kk*4+5]*h1.y;
        a01 += w0[kk*4+6]*h1.z; a01 += w0[kk*4+7]*h1.w;
        a11 += w1[kk*4+4]*h1.x; a11 += w1[kk*4+5]*h1.y;
        a11 += w1[kk*4+6]*h1.z; a11 += w1[kk*4+7]*h1.w;
      }
      acc0[b] = a00 + a01;
      acc1[b] = a10 + a11;
    }

    #pragma unroll
    for (int m = 1; m < 8; m <<= 1) {
      #pragma unroll
      for (int b = 0; b < 4; ++b) {
        acc0[b] += __shfl_xor(acc0[b], m, 64);
        acc1[b] += __shfl_xor(acc1[b], m, 64);
      }
    }
    if (s < 4) {
      float v0 = (s & 2) ? ((s & 1) ? acc0[3] : acc0[2])
                         : ((s & 1) ? acc0[1] : acc0[0]);
      float v1 = (s & 2) ? ((s & 1) ? acc1[3] : acc1[2])
                         : ((s & 1) ? acc1[1] : acc1[0]);
      ghsh[r0 * 5 + s] = v0;
      ghsh[r1 * 5 + s] = v1;
    }
    __syncthreads();

    if (tid < 128) {
      int bb = tid >> 5, j = tid & 31;
      float ghr = ghsh[ j       * 5 + bb] + bsh[j];
      float ghz = ghsh[(32 + j) * 5 + bb] + bsh[32 + j];
      float ghn = ghsh[(64 + j) * 5 + bb] + bsh[64 + j];
      float rg = 1.f / (1.f + expf(-(gxr + ghr)));
      float zg = 1.f / (1.f + expf(-(gxz + ghz)));
      float ng = tanhf(gxn + rg * ghn);
      float hp = hsh[bb * HSTR + j0 + j];
      float hnew = (1.f - zg) * ng + zg * hp;
      __hip_atomic_store(&hist[((size_t)(bbase + bb) * T_ + t) * H_ + j0 + j],
                         hnew, __ATOMIC_RELAXED, __HIP_MEMORY_SCOPE_AGENT);
    }

    asm volatile("s_waitcnt vmcnt(0)" ::: "memory");
    __syncthreads();
    if (tid == 0)
      __hip_atomic_store(&gflags[c], t + 1, __ATOMIC_RELAXED,
                         __HIP_MEMORY_SCOPE_AGENT);
    if (tid < 16) {
      while (__hip_atomic_load(&gflags[tid], __ATOMIC_RELAXED,
                               __HIP_MEMORY_SCOPE_AGENT) < t + 1) {}
    }
    __syncthreads();
    asm volatile("" ::: "memory");
  }
}

// ---------------- fp32 -> bf16 hi/lo split ----------------
__device__ __forceinline__ unsigned short f2bf_rne(float f) {
  unsigned u = __float_as_uint(f);
  unsigned r = (u + 0x7fffu + ((u >> 16) & 1u)) >> 16;
  return (unsigned short)r;
}
__device__ __forceinline__ float bf2f(unsigned short h) {
  return __uint_as_float(((unsigned)h) << 16);
}

// Splits A (with (b,t)->row remap) into hi/lo bf16 planes. For plain matrices
// pass t0=0, tc=1<<30, ltc=30 (identity mapping).
__global__ __launch_bounds__(256) void conv_split(
    const float* __restrict__ A, int lda, int t0, int tc, int ltc,
    unsigned short* __restrict__ Ah, unsigned short* __restrict__ Al)
{
  int idx = blockIdx.x * 256 + threadIdx.x;
  int m = idx / (lda >> 2), kq = idx % (lda >> 2);
  const float4 v = *(const float4*)
      (A + ((size_t)(m >> ltc) * T_ + t0 + (m & (tc - 1))) * lda + (kq << 2));
  unsigned short h0 = f2bf_rne(v.x), h1 = f2bf_rne(v.y),
                 h2 = f2bf_rne(v.z), h3 = f2bf_rne(v.w);
  unsigned short l0 = f2bf_rne(v.x - bf2f(h0)), l1 = f2bf_rne(v.y - bf2f(h1)),
                 l2 = f2bf_rne(v.z - bf2f(h2)), l3 = f2bf_rne(v.w - bf2f(h3));
  size_t o = (size_t)m * lda + (kq << 2);
  *(ushort4*)(Ah + o) = make_ushort4(h0, h1, h2, h3);
  *(ushort4*)(Al + o) = make_ushort4(l0, l1, l2, l3);
}

// ---------------- split-bf16 MFMA GEMM ----------------
// C[m][n] = A[m][:]*B[n][:] + bias[n], A ~ Ah+Al, B ~ Bh+Bl;
// C ~= Ah*Bh + Ah*Bl + Al*Bh (fp32 accum). 128x128 tile, BK=32, 4 waves 2x2.
__global__ __launch_bounds__(256, 2) void gemm_mfma(
    const unsigned short* __restrict__ Ah, const unsigned short* __restrict__ Al,
    const unsigned short* __restrict__ Bh, const unsigned short* __restrict__ Bl,
    const float* __restrict__ bias, float* __restrict__ gxout, int K)
{
  __shared__ unsigned short sAh[128 * BK], sAl[128 * BK];
  __shared__ unsigned short sBh[128 * BK], sBl[128 * BK];

  const int tid = threadIdx.x;
  const int m0 = blockIdx.x << 7, n0 = blockIdx.y << 7;
  const int wave = tid >> 6, lane = tid & 63;
  const int wr = (wave & 1) << 6, wc = (wave >> 1) << 6;
  const int fm = lane & 15, kh = lane >> 4;           // frag row / k-half

  f32x4 acc[4][4];
  #pragma unroll
  for (int i = 0; i < 4; ++i)
    #pragma unroll
    for (int j = 0; j < 4; ++j)
      acc[i][j] = (f32x4){0.f, 0.f, 0.f, 0.f};

  const int ch0 = tid << 1;                 // 2 16B-chunks per thread per tile
  const int r0c = ch0 >> 2, q0 = ch0 & 3;
  const int r1c = (ch0 + 1) >> 2, q1 = (ch0 + 1) & 3;

  for (int k0 = 0; k0 < K; k0 += BK) {
    __syncthreads();
    {
      size_t ga0 = (size_t)(m0 + r0c) * K + k0 + (q0 << 3);
      size_t ga1 = (size_t)(m0 + r1c) * K + k0 + (q1 << 3);
      size_t gb0 = (size_t)(n0 + r0c) * K + k0 + (q0 << 3);
      size_t gb1 = (size_t)(n0 + r1c) * K + k0 + (q1 << 3);
      int la0 = r0c * BK + (q0 << 3), la1 = r1c * BK + (q1 << 3);
      *(float4*)&sAh[la0] = *(const float4*)&Ah[ga0];
      *(float4*)&sAh[la1] = *(const float4*)&Ah[ga1];
      *(float4*)&sAl[la0] = *(const float4*)&Al[ga0];
      *(float4*)&sAl[la1] = *(const float4*)&Al[ga1];
      *(float4*)&sBh[la0] = *(const float4*)&Bh[gb0];
      *(float4*)&sBh[la1] = *(const float4*)&Bh[gb1];
      *(float4*)&sBl[la0] = *(const float4*)&Bl[gb0];
      *(float4*)&sBl[la1] = *(const float4*)&Bl[gb1];
    }
    __syncthreads();

    short8 fAh[4], fAl[4], fBh[4], fBl[4];
    #pragma unroll
    for (int i = 0; i < 4; ++i) {
      int ao = (wr + i * 16 + fm) * BK + (kh << 3);
      int bo = (wc + i * 16 + fm) * BK + (kh << 3);
      fAh[i] = *(const short8*)&sAh[ao];
      fAl[i] = *(const short8*)&sAl[ao];
      fBh[i] = *(const short8*)&sBh[bo];
      fBl[i] = *(const short8*)&sBl[bo];
    }
    #pragma unroll
    for (int i = 0; i < 4; ++i)
      #pragma unroll
      for (int j = 0; j < 4; ++j) {
        acc[i][j] = __builtin_amdgcn_mfma_f32_16x16x32_bf16(
            fAh[i], fBh[j], acc[i][j], 0, 0, 0);
        acc[i][j] = __builtin_amdgcn_mfma_f32_16x16x32_bf16(
            fAh[i], fBl[j], acc[i][j], 0, 0, 0);
        acc[i][j] = __builtin_amdgcn_mfma_f32_16x16x32_bf16(
            fAl[i], fBh[j], acc[i][j], 0, 0, 0);
      }
  }

  #pragma unroll
  for (int j = 0; j < 4; ++j) {
    int col = n0 + wc + j * 16 + fm;
    float bv = bias[col];
    #pragma unroll
    for (int i = 0; i < 4; ++i) {
      int rowb = m0 + wr + i * 16 + (kh << 2);
      #pragma unroll
      for (int r = 0; r < 4; ++r)
        gxout[(size_t)(rowb + r) * G3_ + col] = acc[i][j][r] + bv;
    }
  }
}

// ---------------- final FC ----------------
__global__ void fc_kernel(const float* __restrict__ hist, const float* __restrict__ Wfc,
                          const float* __restrict__ bfc, float* __restrict__ out)
{
  int b = blockIdx.x, lane = threadIdx.x;
  const float* h = hist + ((size_t)b*T_ + (T_-1))*H_;
  float acc = 0.f;
  for (int j = lane; j < H_; j += 64) acc += h[j]*Wfc[j];
  #pragma unroll
  for (int off = 32; off; off >>= 1) acc += __shfl_down(acc, off, 64);
  if (lane == 0) out[b] = acc + bfc[0];
}

__global__ void init_kernel(int* flags) {
  if (threadIdx.x < 512) flags[threadIdx.x] = 0;
}

extern "C" void kernel_launch(void* const* d_in, const int* in_sizes, int n_in,
                              void* d_out, int out_size, void* d_ws, size_t ws_size,
                              hipStream_t stream)
{
  const float* X    = (const float*)d_in[0];
  const float* Wih0 = (const float*)d_in[1];
  const float* Whh0 = (const float*)d_in[2];
  const float* bih0 = (const float*)d_in[3];
  const float* bhh0 = (const float*)d_in[4];
  const float* Wih1 = (const float*)d_in[5];
  const float* Whh1 = (const float*)d_in[6];
  const float* bih1 = (const float*)d_in[7];
  const float* bhh1 = (const float*)d_in[8];
  const float* Wfc  = (const float*)d_in[9];
  const float* bfc  = (const float*)d_in[10];

  int* flags = (int*)d_ws;
  float* hist = (float*)((char*)d_ws + 4096);
  const size_t histB = (size_t)B_*T_*H_*4;

  // choose chunk size tc by workspace budget:
  // need: 4K + hist(64M) + gx(B*tc*G3*4) + Ah/Al(B*tc*512*2 each) + Bh/Bl(1536*512*2 each)
  const size_t bB = (size_t)G3_ * 512 * 2;
  int tc = 128;
  {
    size_t fixed = 4096 + histB + 2 * bB;
    if      (ws_size >= fixed + (size_t)B_*512*((size_t)G3_*4 + 512*4)) tc = 512;
    else if (ws_size >= fixed + (size_t)B_*256*((size_t)G3_*4 + 512*4)) tc = 256;
  }
  int ltc = 31 - __builtin_clz((unsigned)tc);

  float* gxbuf = (float*)((char*)d_ws + 4096 + histB);
  const size_t gxB = (size_t)B_*tc*G3_*4;
  unsigned short* Ahb = (unsigned short*)((char*)gxbuf + gxB);
  const size_t aB = (size_t)B_*tc*512*2;
  unsigned short* Alb = (unsigned short*)((char*)Ahb + aB);
  unsigned short* Bhb = (unsigned short*)((char*)Alb + aB);
  unsigned short* Blb = (unsigned short*)((char*)Bhb + bB);

  hipLaunchKernelGGL(init_kernel, dim3(1), dim3(512), 0, stream, flags);

  for (int lay = 0; lay < 2; ++lay) {
    const float* A   = lay ? (const float*)hist : X;
    int lda          = lay ? H_ : D0_;
    const float* Wih = lay ? Wih1 : Wih0;
    const float* bih = lay ? bih1 : bih0;
    const float* Whh = lay ? Whh1 : Whh0;
    const float* bhh = lay ? bhh1 : bhh0;
    int* lflags = flags + lay*256;

    // split W_ih once per layer (identity row mapping)
    hipLaunchKernelGGL(conv_split, dim3((G3_*lda/4)/256), dim3(256), 0, stream,
                       Wih, lda, 0, 1 << 30, 30, Bhb, Blb);

    for (int t0 = 0; t0 < T_; t0 += tc) {
      int M = B_ * tc;
      hipLaunchKernelGGL(conv_split, dim3((M*lda/4)/256), dim3(256), 0, stream,
                         A, lda, t0, tc, ltc, Ahb, Alb);
      dim3 ggrid(M >> 7, G3_ >> 7);
      hipLaunchKernelGGL(gemm_mfma, ggrid, dim3(256), 0, stream,
                         Ahb, Alb, Bhb, Blb, bih, gxbuf, lda);
      const float* gxc = gxbuf;
      int t0a = t0, tca = tc;
      void* args[] = { (void*)&Whh, (void*)&bhh, (void*)&gxc, (void*)&hist,
                       (void*)&lflags, (void*)&t0a, (void*)&tca };
      hipLaunchCooperativeKernel((void*)scan_kernel, dim3(256), dim3(384),
                                 args, 0, stream);
    }
  }

  hipLaunchKernelGGL(fc_kernel, dim3(64), dim3(64), 0, stream,
                     (const float*)hist, Wfc, bfc, (float*)d_out);
}